// Round 18
// baseline (614.292 us; speedup 1.0000x reference)
//
#include <hip/hip_runtime.h>
#include <hip/hip_cooperative_groups.h>
#include <math.h>

namespace cg = cooperative_groups;

constexpr int B  = 128;
constexpr int R  = 4096;
constexpr int IC = 8;
constexpr int C  = 10;
constexpr int O  = 16;
constexpr int CO = C * O;        // 160

constexpr int RCH    = 16;       // r's per chunk (R12 proven geometry)
constexpr int NCHUNK = R / RCH;  // 256
constexpr int NBLK   = 256;      // coop grid: R9-validated size; 512 thr/block
constexpr int NWCONV8 = (R * C * O * IC) / 2048;  // 2560 fallback W-convert blocks
constexpr int NXPOSE  = (R / 16) * (B / 16);      // 2048 x-transpose units

using f16x8 = __attribute__((ext_vector_type(8))) _Float16;
using f16x4 = __attribute__((ext_vector_type(4))) _Float16;
using f32x4 = __attribute__((ext_vector_type(4))) float;

// DPP add (VALU). row_ror:N = 0x120|N rotates within each 16-lane row.
template<int CTRL>
__device__ __forceinline__ float dpp_add(float v) {
    return v + __int_as_float(__builtin_amdgcn_update_dpp(
        0, __float_as_int(v), CTRL, 0xF, 0xF, true));
}
__device__ __forceinline__ float rowsum16(float v) {
    v = dpp_add<0x121>(v); v = dpp_add<0x122>(v);
    v = dpp_add<0x124>(v); v = dpp_add<0x128>(v);
    return v;
}

// Butterfly sum over lane^16 / lane^32 (R12-proven DS path).
__device__ __forceinline__ float sum_kb(float p) {
    p += __int_as_float(__builtin_amdgcn_ds_swizzle(__float_as_int(p), 0x401F));
    p += __shfl_xor(p, 32, 64);
    return p;
}

// ---- shared device bodies (identical math to the 101 us R12 kernels) ----

__device__ __forceinline__ void wconv8(size_t i, const float* __restrict__ W,
                                       _Float16* __restrict__ W16)
{
    float4 v0 = *reinterpret_cast<const float4*>(W + i);
    float4 v1 = *reinterpret_cast<const float4*>(W + i + 4);
    f16x8 h = {(_Float16)v0.x, (_Float16)v0.y, (_Float16)v0.z, (_Float16)v0.w,
               (_Float16)v1.x, (_Float16)v1.y, (_Float16)v1.z, (_Float16)v1.w};
    *reinterpret_cast<f16x8*>(W16 + i) = h;
}

// one 16x16 (b,r) tile of x -> xT16 [r][b][i]; tid in [0,256)
__device__ __forceinline__ void xpose_body(int v2, int tid,
                                           const float* __restrict__ x,
                                           _Float16* __restrict__ xT16,
                                           float (*tile)[16][IC + 1])
{
    const int r0 = (v2 & 255) * 16;
    const int b0 = (v2 >> 8) * 16;
    {
        const int rj = tid & 15, bi = tid >> 4;   // coalesced read over r
        const float* src = x + ((size_t)(b0 + bi) * R + (r0 + rj)) * IC;
        float4 a0 = *reinterpret_cast<const float4*>(src);
        float4 a1 = *reinterpret_cast<const float4*>(src + 4);
        float* t = tile[bi][rj];
        t[0]=a0.x; t[1]=a0.y; t[2]=a0.z; t[3]=a0.w;
        t[4]=a1.x; t[5]=a1.y; t[6]=a1.z; t[7]=a1.w;
    }
    __syncthreads();
    {
        const int bi = tid & 15, rj = tid >> 4;   // coalesced write over b
        const float* t = tile[bi][rj];
        f16x8 h;
        #pragma unroll
        for (int i = 0; i < IC; ++i) h[i] = (_Float16)t[i];
        *reinterpret_cast<f16x8*>(xT16 + ((size_t)(r0 + rj) * B + (b0 + bi)) * IC) = h;
    }
    __syncthreads();                              // tile reuse fence
}

// pass 0: K-packed GEMM (uniform 0.1 weights). g in [0,512), tid in [0,256).
__device__ __forceinline__ void pass0_body(
    int g, int tid, const _Float16* __restrict__ W16,
    const _Float16* __restrict__ xT16, float* __restrict__ s_part)
{
    const int wv = tid >> 6, l = tid & 63, ln = l & 15, kb = l >> 4;
    const int xcd = g & 7, t = g >> 3;
    const int bhalf = t & 1, cid = t >> 1;
    const int chunk = xcd * 32 + cid;          // 0..255
    const int b  = bhalf * 64 + wv * 16 + ln;
    const int r0 = chunk * RCH;

    f32x4 sacc[C];
    #pragma unroll
    for (int c = 0; c < C; ++c) sacc[c] = (f32x4){0.f, 0.f, 0.f, 0.f};

    const _Float16* xptr = xT16 + ((size_t)(r0 + kb) * B + b) * IC;
    const _Float16* wptr = W16 + ((size_t)(r0 + kb) * C * O + ln) * IC;

    #pragma unroll 2
    for (int rp = 0; rp < RCH / 4; ++rp) {
        const f16x8 bf = *reinterpret_cast<const f16x8*>(xptr);
        xptr += (size_t)4 * B * IC;
        #pragma unroll
        for (int c = 0; c < C; ++c) {
            f16x8 af = *reinterpret_cast<const f16x8*>(wptr + (size_t)c * (O * IC));
            sacc[c] = __builtin_amdgcn_mfma_f32_16x16x32_f16(af, bf, sacc[c], 0, 0, 0);
        }
        wptr += (size_t)4 * C * O * IC;
    }

    float* sp = s_part + ((size_t)chunk * B + b) * CO + kb * 4;
    #pragma unroll
    for (int c = 0; c < C; ++c)
        *reinterpret_cast<float4*>(sp + c * O) =
            make_float4(sacc[c][0] * 0.1f, sacc[c][1] * 0.1f,
                        sacc[c][2] * 0.1f, sacc[c][3] * 0.1f);
}

// routing pass (iters 1,2): masked bf, DS butterfly, rcp softmax, unroll 2.
__device__ __forceinline__ void pass_body(
    int g, int tid, const _Float16* __restrict__ W16,
    const _Float16* __restrict__ xT16, const float* __restrict__ vsum,
    float* __restrict__ s_part)
{
    const int wv = tid >> 6, l = tid & 63, ln = l & 15, kb = l >> 4;
    const int xcd = g & 7, t = g >> 3;
    const int bhalf = t & 1, cid = t >> 1;
    const int chunk = xcd * 32 + cid;          // 0..255
    const int b  = bhalf * 64 + wv * 16 + ln;
    const int r0 = chunk * RCH;

    float vreg[C][4];                  // v[b][c][o = kb*4 + j]
    #pragma unroll
    for (int c = 0; c < C; ++c)
        *reinterpret_cast<float4*>(vreg[c]) =
            *reinterpret_cast<const float4*>(vsum + (size_t)b * CO + c * O + kb * 4);

    f32x4 sacc[C];
    #pragma unroll
    for (int c = 0; c < C; ++c) sacc[c] = (f32x4){0.f, 0.f, 0.f, 0.f};

    const _Float16* xptr = xT16 + ((size_t)r0 * B + b) * IC;
    const _Float16* wptr = W16 + ((size_t)r0 * C * O + ln) * IC;

    #pragma unroll 2
    for (int rr = 0; rr < RCH; ++rr) {
        f16x8 bf;
        #pragma unroll
        for (int j = 0; j < 8; ++j) bf[j] = (_Float16)0.f;
        if (kb == 0) bf = *reinterpret_cast<const f16x8*>(xptr);
        xptr += (size_t)B * IC;

        f32x4 uh[C];
        #pragma unroll
        for (int c = 0; c < C; ++c) {
            f16x8 af = *reinterpret_cast<const f16x8*>(wptr + (size_t)c * (O * IC));
            uh[c] = __builtin_amdgcn_mfma_f32_16x16x32_f16(
                        af, bf, (f32x4){0.f, 0.f, 0.f, 0.f}, 0, 0, 0);
        }
        wptr += C * O * IC;

        float a[C];
        #pragma unroll
        for (int c = 0; c < C; ++c) {
            float p = uh[c][0] * vreg[c][0];
            p = fmaf(uh[c][1], vreg[c][1], p);
            p = fmaf(uh[c][2], vreg[c][2], p);
            p = fmaf(uh[c][3], vreg[c][3], p);
            a[c] = sum_kb(p);
        }
        float sum = 0.f;
        #pragma unroll
        for (int c = 0; c < C; ++c) { a[c] = __expf(a[c]); sum += a[c]; }
        const float inv = __builtin_amdgcn_rcpf(sum);
        #pragma unroll
        for (int c = 0; c < C; ++c) {
            const float wgt = a[c] * inv;
            #pragma unroll
            for (int j = 0; j < 4; ++j)
                sacc[c][j] = fmaf(wgt, uh[c][j], sacc[c][j]);
        }
    }

    float* sp = s_part + ((size_t)chunk * B + b) * CO + kb * 4;
    #pragma unroll
    for (int c = 0; c < C; ++c)
        *reinterpret_cast<float4*>(sp + c * O) =
            make_float4(sacc[c][0], sacc[c][1], sacc[c][2], sacc[c][3]);
}

// reduce + squash for one (b,c) unit; tid in [0,256)
__device__ __forceinline__ void reduce_body(
    int u, int tid, const float* __restrict__ s_part, const float* __restrict__ bias,
    const float* __restrict__ vin_sum, float* __restrict__ v_out,
    float* __restrict__ vsum_out, float (*red)[O])
{
    const int b = u & 127;
    const int c = u >> 7;
    const int o = tid & 15;
    const int q = tid >> 4;          // 16 segments of 16 chunks

    float acc = 0.f;
    #pragma unroll 4
    for (int k = 0; k < NCHUNK / 16; ++k) {
        const int blk = q * (NCHUNK / 16) + k;
        acc += s_part[((size_t)blk * B + b) * CO + c * O + o];
    }
    red[q][o] = acc;
    __syncthreads();

    if (tid < O) {
        float s = bias[c * O + o];
        #pragma unroll
        for (int k = 0; k < 16; ++k) s += red[k][o];
        float n = rowsum16(s * s);                     // ||s||^2 over o
        float v = s * sqrtf(n) / (1.f + n);            // squash
        const size_t idx = (size_t)b * CO + c * O + o;
        if (v_out)    v_out[idx] = v;
        if (vsum_out) vsum_out[idx] = (vin_sum ? vin_sum[idx] : 0.f) + v;
    }
    __syncthreads();                 // red reuse fence
}

// ---- cooperative whole-op kernel: 256 blocks x 512 threads.
// Each block hosts TWO logical R12 blocks (glog = blockIdx*2 + tid>>8), so
// per-CU residency = 8 waves = exactly R12's. Grid 256 = R9-validated coop size.
__global__ void __launch_bounds__(512, 2)
digitcaps_coop(const float* __restrict__ x, const float* __restrict__ W,
               const float* __restrict__ bias, float* __restrict__ out,
               float* __restrict__ s_part, float* __restrict__ vsumA,
               float* __restrict__ vsumB, _Float16* __restrict__ W16,
               _Float16* __restrict__ xT16)
{
    cg::grid_group grid = cg::this_grid();
    const int t512 = threadIdx.x;
    const int half = t512 >> 8;
    const int tid  = t512 & 255;
    const int glog = blockIdx.x * 2 + half;     // 0..511: R12's logical block id

    __shared__ float tile[2][16][16][IC + 1];   // 18.4 KB (convert)
    __shared__ float red[2][16][O];             // 2 KB   (reduce)

    // phase A: W -> fp16, 5 sweeps x 8 floats (exactly covers 5,242,880)
    {
        const size_t base = ((size_t)blockIdx.x * 512 + t512) * 8;
        #pragma unroll
        for (int s = 0; s < 5; ++s)
            wconv8(base + (size_t)s * ((size_t)NBLK * 512 * 8), W, W16);
    }
    // phase A2: x transpose, 4 tiles per logical half (2048 total)
    for (int it = 0; it < 4; ++it)
        xpose_body(glog + it * 512, tid, x, xT16, tile[half]);
    __threadfence();
    grid.sync();

    // iter 0
    pass0_body(glog, tid, W16, xT16, s_part);
    __threadfence();
    grid.sync();
    for (int u = glog; u < B * C; u += 512)
        reduce_body(u, tid, s_part, bias, nullptr, nullptr, vsumA, red[half]);
    __threadfence();
    grid.sync();

    // iter 1: logits = uh . v0
    pass_body(glog, tid, W16, xT16, vsumA, s_part);
    __threadfence();
    grid.sync();
    for (int u = glog; u < B * C; u += 512)
        reduce_body(u, tid, s_part, bias, vsumA, nullptr, vsumB, red[half]);
    __threadfence();
    grid.sync();

    // iter 2: logits = uh . (v0+v1)
    pass_body(glog, tid, W16, xT16, vsumB, s_part);
    __threadfence();
    grid.sync();
    for (int u = glog; u < B * C; u += 512)
        reduce_body(u, tid, s_part, bias, nullptr, out, nullptr, red[half]);
}

// ---- fallback wrappers: exact R12 multi-launch path ----
__global__ __launch_bounds__(256)
void k_convert(const float* __restrict__ x, const float* __restrict__ W,
               _Float16* __restrict__ W16, _Float16* __restrict__ xT16)
{
    __shared__ float tile[16][16][IC + 1];
    const int bid = blockIdx.x, tid = threadIdx.x;
    if (bid < NWCONV8) wconv8(((size_t)bid * 256 + tid) * 8, W, W16);
    else               xpose_body(bid - NWCONV8, tid, x, xT16, tile);
}
__global__ __launch_bounds__(256, 4)
void k_pass0(const _Float16* __restrict__ W16, const _Float16* __restrict__ xT16,
             float* __restrict__ s_part)
{ pass0_body(blockIdx.x, threadIdx.x, W16, xT16, s_part); }

__global__ __launch_bounds__(256, 3)
void k_pass(const _Float16* __restrict__ W16, const _Float16* __restrict__ xT16,
            const float* __restrict__ vsum, float* __restrict__ s_part)
{ pass_body(blockIdx.x, threadIdx.x, W16, xT16, vsum, s_part); }

__global__ __launch_bounds__(256)
void k_reduce(const float* __restrict__ s_part, const float* __restrict__ bias,
              const float* __restrict__ vin, float* __restrict__ vout_v,
              float* __restrict__ vout_s)
{
    __shared__ float red[16][O];
    reduce_body(blockIdx.x, threadIdx.x, s_part, bias, vin, vout_v, vout_s, red);
}

extern "C" void kernel_launch(void* const* d_in, const int* in_sizes, int n_in,
                              void* d_out, int out_size, void* d_ws, size_t ws_size,
                              hipStream_t stream)
{
    const float* x    = (const float*)d_in[0];
    const float* W    = (const float*)d_in[1];
    const float* bias = (const float*)d_in[2];
    float* out = (float*)d_out;

    float* ws     = (float*)d_ws;
    float* s_part = ws;                                     // 256*128*160 f (21 MB)
    float* vsumA  = s_part + (size_t)NCHUNK * B * CO;       // 20,480 f
    float* vsumB  = vsumA + (size_t)B * CO;                 // 20,480 f
    _Float16* W16  = (_Float16*)(vsumB + (size_t)B * CO);   // 5,242,880 halves
    _Float16* xT16 = W16 + (size_t)R * C * O * IC;          // 4,194,304 halves
    // total ~40 MB

    void* args[] = {(void*)&x, (void*)&W, (void*)&bias, (void*)&out,
                    (void*)&s_part, (void*)&vsumA, (void*)&vsumB,
                    (void*)&W16, (void*)&xT16};
    hipError_t e = hipLaunchCooperativeKernel(
        reinterpret_cast<void*>(digitcaps_coop), dim3(NBLK), dim3(512), args, 0, stream);

    if (e != hipSuccess) {           // deterministic fallback: proven R12 path
        (void)hipGetLastError();     // clear sticky error
        k_convert<<<NWCONV8 + NXPOSE, 256, 0, stream>>>(x, W, W16, xT16);
        k_pass0<<<512, 256, 0, stream>>>(W16, xT16, s_part);
        k_reduce<<<B * C, 256, 0, stream>>>(s_part, bias, nullptr, nullptr, vsumA);
        k_pass<<<512, 256, 0, stream>>>(W16, xT16, vsumA, s_part);
        k_reduce<<<B * C, 256, 0, stream>>>(s_part, bias, vsumA, nullptr, vsumB);
        k_pass<<<512, 256, 0, stream>>>(W16, xT16, vsumB, s_part);
        k_reduce<<<B * C, 256, 0, stream>>>(s_part, bias, nullptr, out, nullptr);
    }
}

// Round 19
// 90.684 us; speedup vs baseline: 6.7740x; 6.7740x over previous
//
#include <hip/hip_runtime.h>
#include <math.h>

constexpr int B  = 128;
constexpr int R  = 4096;
constexpr int IC = 8;
constexpr int C  = 10;
constexpr int O  = 16;
constexpr int CO = C * O;        // 160

constexpr int RCH    = 16;       // r's per chunk (101-us proven geometry)
constexpr int NCHUNK = R / RCH;  // 256
constexpr int NWCONV = (R * C * O * IC) / 1024;   // 5120 W-convert blocks
constexpr int NXPOSE = (R / 16) * (B / 16);       // 2048 x-transpose blocks

using f16x8 = __attribute__((ext_vector_type(8))) _Float16;
using f16x4 = __attribute__((ext_vector_type(4))) _Float16;
using f32x4 = __attribute__((ext_vector_type(4))) float;

// DPP add (VALU). row_ror:N = 0x120|N rotates within each 16-lane row.
template<int CTRL>
__device__ __forceinline__ float dpp_add(float v) {
    return v + __int_as_float(__builtin_amdgcn_update_dpp(
        0, __float_as_int(v), CTRL, 0xF, 0xF, true));
}
__device__ __forceinline__ float rowsum16(float v) {
    v = dpp_add<0x121>(v); v = dpp_add<0x122>(v);
    v = dpp_add<0x124>(v); v = dpp_add<0x128>(v);
    return v;
}

// Butterfly sum over lane^16 / lane^32 (proven DS path).
__device__ __forceinline__ float sum_kb(float p) {
    p += __int_as_float(__builtin_amdgcn_ds_swizzle(__float_as_int(p), 0x401F));
    p += __shfl_xor(p, 32, 64);
    return p;
}

// ---- fused one-time converts: W fp32->fp16 (same layout) + x -> xT16 [r][b][i] ----
__global__ __launch_bounds__(256)
void convert_kernel(const float* __restrict__ x, const float* __restrict__ W,
                    _Float16* __restrict__ W16, _Float16* __restrict__ xT16)
{
    const int bid = blockIdx.x;
    const int tid = threadIdx.x;
    if (bid < NWCONV) {
        const size_t i = ((size_t)bid * 256 + tid) * 4;
        float4 v = *reinterpret_cast<const float4*>(W + i);
        f16x4 h = {(_Float16)v.x, (_Float16)v.y, (_Float16)v.z, (_Float16)v.w};
        *reinterpret_cast<f16x4*>(W16 + i) = h;
    } else {
        __shared__ float tile[16][16][IC + 1];
        const int v  = bid - NWCONV;
        const int r0 = (v & 255) * 16;
        const int b0 = (v >> 8) * 16;
        {
            const int rj = tid & 15, bi = tid >> 4;   // coalesced read over r
            const float* src = x + ((size_t)(b0 + bi) * R + (r0 + rj)) * IC;
            float4 a0 = *reinterpret_cast<const float4*>(src);
            float4 a1 = *reinterpret_cast<const float4*>(src + 4);
            float* t = tile[bi][rj];
            t[0]=a0.x; t[1]=a0.y; t[2]=a0.z; t[3]=a0.w;
            t[4]=a1.x; t[5]=a1.y; t[6]=a1.z; t[7]=a1.w;
        }
        __syncthreads();
        {
            const int bi = tid & 15, rj = tid >> 4;   // coalesced write over b
            const float* t = tile[bi][rj];
            f16x8 h;
            #pragma unroll
            for (int i = 0; i < IC; ++i) h[i] = (_Float16)t[i];
            *reinterpret_cast<f16x8*>(xT16 + ((size_t)(r0 + rj) * B + (b0 + bi)) * IC) = h;
        }
    }
}

// ---- pass 0: K-packed GEMM (uniform 0.1 weights => per-r sum collapses).
// 4 r's per MFMA K=32; every lane loads real 16B; zero K-waste. Unchanged. ----
__global__ __launch_bounds__(256, 4)
void pass0_gemm(const _Float16* __restrict__ W16, const _Float16* __restrict__ xT16,
                float* __restrict__ s_part)
{
    const int tid = threadIdx.x;
    const int wv  = tid >> 6;
    const int l   = tid & 63;
    const int ln  = l & 15;
    const int kb  = l >> 4;

    const int g     = blockIdx.x;
    const int xcd   = g & 7;
    const int t     = g >> 3;          // 0..63
    const int bhalf = t & 1;
    const int cid   = t >> 1;          // 0..31
    const int chunk = xcd * 32 + cid;  // 0..255
    const int b     = bhalf * 64 + wv * 16 + ln;
    const int r0    = chunk * RCH;

    f32x4 sacc[C];
    #pragma unroll
    for (int c = 0; c < C; ++c) sacc[c] = (f32x4){0.f, 0.f, 0.f, 0.f};

    const _Float16* xptr = xT16 + ((size_t)(r0 + kb) * B + b) * IC;
    const _Float16* wptr = W16 + ((size_t)(r0 + kb) * C * O + ln) * IC;

    #pragma unroll 2
    for (int rp = 0; rp < RCH / 4; ++rp) {
        const f16x8 bf = *reinterpret_cast<const f16x8*>(xptr);
        xptr += (size_t)4 * B * IC;
        #pragma unroll
        for (int c = 0; c < C; ++c) {
            f16x8 af = *reinterpret_cast<const f16x8*>(wptr + (size_t)c * (O * IC));
            sacc[c] = __builtin_amdgcn_mfma_f32_16x16x32_f16(af, bf, sacc[c], 0, 0, 0);
        }
        wptr += (size_t)4 * C * O * IC;
    }

    float* sp = s_part + ((size_t)chunk * B + b) * CO + kb * 4;
    #pragma unroll
    for (int c = 0; c < C; ++c)
        *reinterpret_cast<float4*>(sp + c * O) =
            make_float4(sacc[c][0] * 0.1f, sacc[c][1] * 0.1f,
                        sacc[c][2] * 0.1f, sacc[c][3] * 0.1f);
}

// ---- routing pass (iters 1,2) with LDS-staged operands ----
// Block stages its whole W slice (40 KB) + x slice (16 KB) into LDS coalesced,
// then the rr loop reads fragments via ds_read_b128 (low, hideable latency)
// instead of ~200-cyc scattered global loads — the stall R12-R16 never fixed.
// Wave = 16 b's; kb = k-block (only kb==0 carries real k; bf zero otherwise).
// D: col=b (ln), row=o (kb*4+reg). unroll 2 = pipelining, no full-unroll spill.
template<int IT>
__global__ __launch_bounds__(256, 2)
void pass_mfma(const _Float16* __restrict__ W16, const _Float16* __restrict__ xT16,
               const float* __restrict__ vsum, float* __restrict__ s_part)
{
    __shared__ _Float16 wlds[RCH * C * O * IC];   // 40 KB: W[r0..r0+15][c][o][i]
    __shared__ _Float16 xlds[RCH * 64 * IC];      // 16 KB: x[r][b-local][i]

    const int tid = threadIdx.x;
    const int wv  = tid >> 6;
    const int l   = tid & 63;
    const int ln  = l & 15;
    const int kb  = l >> 4;

    const int g     = blockIdx.x;
    const int xcd   = g & 7;
    const int t     = g >> 3;          // 0..63
    const int bhalf = t & 1;
    const int cid   = t >> 1;          // 0..31
    const int chunk = xcd * 32 + cid;  // 0..255
    const int b     = bhalf * 64 + wv * 16 + ln;
    const int r0    = chunk * RCH;

    // ---- stage W slice: 40960 halves, 10 sweeps x 256 thr x 16B, coalesced ----
    {
        const _Float16* wsrc = W16 + (size_t)r0 * (C * O * IC);
        #pragma unroll
        for (int k = 0; k < 10; ++k) {
            const int idx = (k * 256 + tid) * 8;
            *reinterpret_cast<f16x8*>(&wlds[idx]) =
                *reinterpret_cast<const f16x8*>(wsrc + idx);
        }
    }
    // ---- stage x slice: 16 r-rows x 64 b x 8i, 4 sweeps x 256 thr, coalesced ----
    {
        const int rr = tid >> 6, lx = tid & 63;
        #pragma unroll
        for (int k = 0; k < 4; ++k) {
            const int r = rr + k * 4;
            *reinterpret_cast<f16x8*>(&xlds[(r * 64 + lx) * IC]) =
                *reinterpret_cast<const f16x8*>(
                    xT16 + ((size_t)(r0 + r) * B + bhalf * 64 + lx) * IC);
        }
    }

    float vreg[C][4];                  // v[b][c][o = kb*4 + j]
    #pragma unroll
    for (int c = 0; c < C; ++c)
        *reinterpret_cast<float4*>(vreg[c]) =
            *reinterpret_cast<const float4*>(vsum + (size_t)b * CO + c * O + kb * 4);

    f32x4 sacc[C];
    #pragma unroll
    for (int c = 0; c < C; ++c) sacc[c] = (f32x4){0.f, 0.f, 0.f, 0.f};

    __syncthreads();                   // staged operands visible

    const int bloc = wv * 16 + ln;     // local b index (0..63)

    #pragma unroll 2
    for (int rr = 0; rr < RCH; ++rr) {
        f16x8 bf;
        #pragma unroll
        for (int j = 0; j < 8; ++j) bf[j] = (_Float16)0.f;
        if (kb == 0)
            bf = *reinterpret_cast<const f16x8*>(&xlds[(rr * 64 + bloc) * IC]);

        f32x4 uh[C];
        #pragma unroll
        for (int c = 0; c < C; ++c) {
            f16x8 af = *reinterpret_cast<const f16x8*>(
                &wlds[((rr * C + c) * O + ln) * IC]);
            uh[c] = __builtin_amdgcn_mfma_f32_16x16x32_f16(
                        af, bf, (f32x4){0.f, 0.f, 0.f, 0.f}, 0, 0, 0);
        }

        // logits a[b,c] = sum_o uh*v: 4 in-lane FMA + DS butterfly
        float a[C];
        #pragma unroll
        for (int c = 0; c < C; ++c) {
            float p = uh[c][0] * vreg[c][0];
            p = fmaf(uh[c][1], vreg[c][1], p);
            p = fmaf(uh[c][2], vreg[c][2], p);
            p = fmaf(uh[c][3], vreg[c][3], p);
            a[c] = sum_kb(p);
        }
        // softmax over c (logits small: no max-subtract), rcp divide
        float sum = 0.f;
        #pragma unroll
        for (int c = 0; c < C; ++c) { a[c] = __expf(a[c]); sum += a[c]; }
        const float inv = __builtin_amdgcn_rcpf(sum);
        #pragma unroll
        for (int c = 0; c < C; ++c) {
            const float wgt = a[c] * inv;
            #pragma unroll
            for (int j = 0; j < 4; ++j)
                sacc[c][j] = fmaf(wgt, uh[c][j], sacc[c][j]);
        }
    }

    float* sp = s_part + ((size_t)chunk * B + b) * CO + kb * 4;
    #pragma unroll
    for (int c = 0; c < C; ++c)
        *reinterpret_cast<float4*>(sp + c * O) =
            make_float4(sacc[c][0], sacc[c][1], sacc[c][2], sacc[c][3]);
}

// Sum partials over chunks, add bias, squash. Block = one (b, c). Unchanged.
__global__ __launch_bounds__(256)
void reduce_squash(const float* __restrict__ s_part, const float* __restrict__ bias,
                   const float* __restrict__ vin_sum,
                   float* __restrict__ v_out, float* __restrict__ vsum_out)
{
    const int b = blockIdx.x;
    const int c = blockIdx.y;
    const int t = threadIdx.x;
    const int o = t & 15;
    const int q = t >> 4;            // 16 segments of NCHUNK/16 chunks

    float acc = 0.f;
    for (int k = 0; k < NCHUNK / 16; ++k) {
        const int blk = q * (NCHUNK / 16) + k;
        acc += s_part[((size_t)blk * B + b) * CO + c * O + o];
    }
    __shared__ float red[16][O];
    red[q][o] = acc;
    __syncthreads();

    if (t < O) {
        float s = bias[c * O + o];
        #pragma unroll
        for (int k = 0; k < 16; ++k) s += red[k][o];
        float n = rowsum16(s * s);                     // ||s||^2 over o
        float v = s * sqrtf(n) / (1.f + n);            // squash
        const size_t idx = (size_t)b * CO + c * O + o;
        if (v_out)    v_out[idx] = v;
        if (vsum_out) vsum_out[idx] = (vin_sum ? vin_sum[idx] : 0.f) + v;
    }
}

extern "C" void kernel_launch(void* const* d_in, const int* in_sizes, int n_in,
                              void* d_out, int out_size, void* d_ws, size_t ws_size,
                              hipStream_t stream)
{
    const float* x    = (const float*)d_in[0];
    const float* W    = (const float*)d_in[1];
    const float* bias = (const float*)d_in[2];
    float* out = (float*)d_out;

    float* ws     = (float*)d_ws;
    float* s_part = ws;                                     // 256*128*160 f (21 MB)
    float* vsumA  = s_part + (size_t)NCHUNK * B * CO;       // 20,480 f
    float* vsumB  = vsumA + (size_t)B * CO;                 // 20,480 f
    _Float16* W16  = (_Float16*)(vsumB + (size_t)B * CO);   // 5,242,880 halves
    _Float16* xT16 = W16 + (size_t)R * C * O * IC;          // 4,194,304 halves
    // total ~40 MB

    convert_kernel<<<NWCONV + NXPOSE, 256, 0, stream>>>(x, W, W16, xT16);

    dim3 pg(NCHUNK * 2);     // 512 blocks, XCD-decoded in-kernel
    dim3 rg(B, C);

    // iter 0: uniform 0.1 weights — K-packed pure GEMM
    pass0_gemm<<<pg, 256, 0, stream>>>(W16, xT16, s_part);
    reduce_squash<<<rg, 256, 0, stream>>>(s_part, bias, nullptr, nullptr, vsumA);  // vsumA = v0
    // iter 1: logits = uh . v0
    pass_mfma<1><<<pg, 256, 0, stream>>>(W16, xT16, vsumA, s_part);
    reduce_squash<<<rg, 256, 0, stream>>>(s_part, bias, vsumA, nullptr, vsumB);    // vsumB = v0+v1
    // iter 2: logits = uh . (v0+v1)
    pass_mfma<2><<<pg, 256, 0, stream>>>(W16, xT16, vsumB, s_part);
    reduce_squash<<<rg, 256, 0, stream>>>(s_part, bias, nullptr, out, nullptr);    // out = v2
}